// Round 7
// baseline (181.939 us; speedup 1.0000x reference)
//
#include <hip/hip_runtime.h>

#define BH_ 32
#define S_ 2048
#define D_ 64
#define DQK 128
#define BQ 256   // q rows per block (8 waves x 32 q-rows each)

typedef unsigned short u16;
typedef unsigned int u32;
typedef u16 u16x8 __attribute__((ext_vector_type(8)));
typedef u32 u32x4 __attribute__((ext_vector_type(4)));
typedef __bf16 bf16x8 __attribute__((ext_vector_type(8)));
typedef float f32x16 __attribute__((ext_vector_type(16)));

__device__ __forceinline__ u16 f2bf_rne(float f) {
  unsigned u = __builtin_bit_cast(unsigned, f);
  u += 0x7fffu + ((u >> 16) & 1u);
  return (u16)(u >> 16);
}
__device__ __forceinline__ bf16x8 ld8(const u16* p) {
  return __builtin_bit_cast(bf16x8, *(const u16x8*)p);
}
// 16B global -> LDS DMA. LDS dest must be wave-uniform base + lane*16.
__device__ __forceinline__ void g2l16(const u16* g, u16* l) {
  __builtin_amdgcn_global_load_lds(
      (const __attribute__((address_space(1))) unsigned int*)g,
      (__attribute__((address_space(3))) unsigned int*)l, 16, 0, 0);
}
__device__ __forceinline__ u32 cvtpk(float lo, float hi) {
  u32 r;
  asm("v_cvt_pk_bf16_f32 %0, %1, %2" : "=v"(r) : "v"(lo), "v"(hi));
  return r;
}
__device__ __forceinline__ void swap32(u32& a, u32& b) {
  asm("v_permlane32_swap_b32 %0, %1" : "+v"(a), "+v"(b));
}
// NOTE (R3/R4 lesson): never feed MFMA accumulator regs straight into inline
// asm (bare v_exp_f32) -- MFMA-dst->VALU-read hazard nops are only inserted
// for compiler-visible consumers; asm uses went unprotected (absmax ~0.17).
// __builtin_amdgcn_exp2f is the compiler-visible bare v_exp_f32: hazard-safe,
// no OCML range-guard sequence (~5 VALU/call saved; scores are bounded).
__device__ __forceinline__ f32x16 zero16() {
  f32x16 z;
  #pragma unroll
  for (int i = 0; i < 16; ++i) z[i] = 0.f;
  return z;
}

#define COEF 0.1803368801111204f  // (1/8) * log2(e), folded into Q conversion

// ---------------- prep ----------------------------------------------------
// Kc: [bh][kt=32][chunk16B=16][kv=64][8 u16]  (chunk = k>>3 of the 128-dim
//     [K|Kp] concat) -> linear DMA image gives conflict-free b128 A-frag reads.
//     Lane mapping: kv fastest -> 16B stores are lane-contiguous (1KB/wave).
// Vt: [bh][kt=32][chunk=8][d=64][8 u16]  where element = V[kt*64+chunk*8+e][d].
__global__ __launch_bounds__(256)
void prep_kernel(const float* __restrict__ K, const float* __restrict__ V,
                 const float* __restrict__ Kp,
                 u16* __restrict__ Kc, u16* __restrict__ Vt) {
  __shared__ float Ls[64][65];
  int b = blockIdx.x;
  if (b < 4096) {
    int t = b * 256 + threadIdx.x;          // 1,048,576 threads
    int kv    = t & 63;
    int chunk = (t >> 6) & 15;
    int kt    = (t >> 10) & 31;
    int bh    = t >> 15;
    int s     = kt * 64 + kv;
    int col8  = chunk * 8;
    const float* src = (col8 < 64) ? (K  + ((size_t)bh * S_ + s) * D_ + col8)
                                   : (Kp + ((size_t)bh * S_ + s) * D_ + (col8 - 64));
    float4 v0 = *(const float4*)src;
    float4 v1 = *(const float4*)(src + 4);
    u16x8 w;
    w[0] = f2bf_rne(v0.x); w[1] = f2bf_rne(v0.y); w[2] = f2bf_rne(v0.z); w[3] = f2bf_rne(v0.w);
    w[4] = f2bf_rne(v1.x); w[5] = f2bf_rne(v1.y); w[6] = f2bf_rne(v1.z); w[7] = f2bf_rne(v1.w);
    *(u16x8*)(Kc + ((((size_t)bh * 32 + kt) * 16 + chunk) * 64 + kv) * 8) = w;
  } else {
    // V transpose: one 64(kv) x 64(d) tile per block via LDS
    int id = b - 4096;
    int bh = id >> 5, kt = id & 31;
    int tid = threadIdx.x;
    #pragma unroll
    for (int it = 0; it < 4; ++it) {
      int i = it * 256 + tid;
      int kv = i >> 4, dg = (i & 15) * 4;
      float4 v = *(const float4*)(V + ((size_t)bh * S_ + kt * 64 + kv) * D_ + dg);
      Ls[kv][dg + 0] = v.x; Ls[kv][dg + 1] = v.y;
      Ls[kv][dg + 2] = v.z; Ls[kv][dg + 3] = v.w;
    }
    __syncthreads();
    int d = tid >> 2, kvg = (tid & 3) * 16;
    u16x8 w0, w1;
    #pragma unroll
    for (int j = 0; j < 8; ++j) w0[j] = f2bf_rne(Ls[kvg + j][d]);
    #pragma unroll
    for (int j = 0; j < 8; ++j) w1[j] = f2bf_rne(Ls[kvg + 8 + j][d]);
    u16* base = Vt + ((size_t)bh * 32 + kt) * 4096;
    int c = (tid & 3) * 2;                   // kv-chunk of w0
    *(u16x8*)(base + ((size_t)(c * 64 + d)) * 8)       = w0;
    *(u16x8*)(base + ((size_t)((c + 1) * 64 + d)) * 8) = w1;
  }
}

// ---------------- flash-attention main kernel -----------------------------
// 32x32x16 MFMA, swapped QK^T (S^T = K.Q^T): lane (hi, q=lane&31) holds
// S^T regs r -> kv = (r&3)+8*(r>>2)+4*hi. P->bf16 + PV A-frags built fully
// in-register via cvt_pk_bf16 + permlane32_swap (no Ps LDS round-trip).
// T4 pipeline (R7): TRIPLE-buffered K/V + counted vmcnt + raw s_barrier.
// Per iter: vmcnt(3) [own tile-t loads done; t+1 in flight] -> s_barrier
// [all waves' t-loads done + all finished compute t-1] -> issue DMA(t+2)
// into buf[(t+2)%3] (== buf[(t-1)%3], free) -> compute t. No vmcnt(0) drain
// in the main loop: loads span barriers, waves de-phase, pipes overlap.
template <int SPLIT>
__global__ __launch_bounds__(512, 4)
void fa3_kernel(const float* __restrict__ Q, const float* __restrict__ Qp,
                const u16* __restrict__ Kc, const u16* __restrict__ Vtg,
                float* __restrict__ out, float* __restrict__ Opart,
                float* __restrict__ lpart) {
  __shared__ alignas(16) u16 Ks[3][8192];   // [buf][chunk=16][kv=64][8]  3x16KB
  __shared__ alignas(16) u16 Vs[3][4096];   // [buf][chunk=8][d=64][8]    3x8KB

  const int tid  = threadIdx.x;
  const int wave = tid >> 6;                // 0..7
  const int lane = tid & 63;
  const int l32  = lane & 31;
  const int hi   = lane >> 5;

  const int id   = blockIdx.x;
  const int p    = SPLIT ? (id & 63) : (id & 31);   // (bh, z) pair index
  const int qblk = SPLIT ? (id >> 6) : (id >> 5);
  const int bh   = p & 31;
  const int kz   = SPLIT ? (p >> 5) : 0;

  const int qw = qblk * BQ + wave * 32;     // this wave's q base
  const int kt0 = kz * 16;
  const int NKT = SPLIT ? 16 : 32;

  // ---- Q B-frags: bq[kstep][j] = Qc[q = qw+l32][kstep*16 + hi*8 + j] ----
  bf16x8 bq[8];
  #pragma unroll
  for (int kstep = 0; kstep < 8; ++kstep) {
    int k0 = kstep * 16 + hi * 8;            // wave-uniform Q/Qp select per kstep
    const float* src = (k0 < 64)
        ? (Q  + ((size_t)bh * S_ + qw + l32) * D_ + k0)
        : (Qp + ((size_t)bh * S_ + qw + l32) * D_ + (k0 - 64));
    float4 v0 = *(const float4*)src;
    float4 v1 = *(const float4*)(src + 4);
    u16x8 w;
    w[0] = f2bf_rne(v0.x * COEF); w[1] = f2bf_rne(v0.y * COEF);
    w[2] = f2bf_rne(v0.z * COEF); w[3] = f2bf_rne(v0.w * COEF);
    w[4] = f2bf_rne(v1.x * COEF); w[5] = f2bf_rne(v1.y * COEF);
    w[6] = f2bf_rne(v1.z * COEF); w[7] = f2bf_rne(v1.w * COEF);
    bq[kstep] = __builtin_bit_cast(bf16x8, w);
  }

  // ---- staging pointers: thread owns 16B at tid-linear offsets ----
  // 512 threads x 16B = 8KB per batch: K tile = 2 batches, V tile = 1.
  // Per tile: exactly 3 g2l16 per thread, fixed order -> FIFO vmcnt counting.
  const u16* kcp = Kc  + ((size_t)bh * 32 + kt0) * 8192 + tid * 8;
  const u16* vtp = Vtg + ((size_t)bh * 32 + kt0) * 4096 + tid * 8;

  // prologue: stage tiles 0 and 1 (NKT >= 2 always)
  #pragma unroll
  for (int j = 0; j < 2; ++j) g2l16(kcp + j * 4096, &Ks[0][0] + tid * 8 + j * 4096);
  g2l16(vtp, &Vs[0][0] + tid * 8);
  #pragma unroll
  for (int j = 0; j < 2; ++j) g2l16(kcp + 8192 + j * 4096, &Ks[1][0] + tid * 8 + j * 4096);
  g2l16(vtp + 4096, &Vs[1][0] + tid * 8);

  f32x16 accd[2];
  accd[0] = zero16(); accd[1] = zero16();
  float l_part = 0.f;

  int cur = 0;                               // kt % 3
  for (int kt = 0; kt < NKT; ++kt) {
    // ---- own tile-kt loads done (tile kt+1's 3 stay in flight) ----
    if (kt == NKT - 1) asm volatile("s_waitcnt vmcnt(0)" ::: "memory");
    else               asm volatile("s_waitcnt vmcnt(3)" ::: "memory");
    // all waves' tile-kt loads landed; all waves finished compute kt-1
    __builtin_amdgcn_s_barrier();
    // ---- issue DMA for tile kt+2 into buf[(kt+2)%3] == buf[(kt-1)%3] ----
    if (kt + 2 < NKT) {
      int nx = cur + 2; if (nx >= 3) nx -= 3;
      const u16* kg = kcp + (size_t)(kt + 2) * 8192;
      u16* kl = &Ks[nx][0] + tid * 8;
      #pragma unroll
      for (int j = 0; j < 2; ++j) g2l16(kg + j * 4096, kl + j * 4096);
      g2l16(vtp + (size_t)(kt + 2) * 4096, &Vs[nx][0] + tid * 8);
    }
    __builtin_amdgcn_sched_barrier(0);  // keep DMA issue ahead of compute

    const u16* ksb = &Ks[cur][0];
    const u16* vsb = &Vs[cur][0];

    // ---- S^T = K . Q^T : two kv-halves of 32, K-dim 128 in 8 steps ----
    f32x16 s[2];
    s[0] = zero16(); s[1] = zero16();
    #pragma unroll
    for (int kstep = 0; kstep < 8; ++kstep) {
      bf16x8 akA = ld8(ksb + (((kstep * 2 + hi) * 64) + l32) * 8);
      bf16x8 akB = ld8(ksb + (((kstep * 2 + hi) * 64) + 32 + l32) * 8);
      s[0] = __builtin_amdgcn_mfma_f32_32x32x16_bf16(akA, bq[kstep], s[0], 0, 0, 0);
      s[1] = __builtin_amdgcn_mfma_f32_32x32x16_bf16(akB, bq[kstep], s[1], 0, 0, 0);
    }

    // ---- softmax numerator + in-register P redistribution + PV ----
    #pragma unroll
    for (int h = 0; h < 2; ++h) {
      float rs0 = 0.f, rs1 = 0.f;          // split chains (reassoc-safe: +)
      #pragma unroll
      for (int r = 0; r < 8; ++r) {
        float e0 = __builtin_amdgcn_exp2f(s[h][r]);
        float e1 = __builtin_amdgcn_exp2f(s[h][8 + r]);
        s[h][r] = e0; s[h][8 + r] = e1;
        rs0 += e0; rs1 += e1;
      }
      l_part += rs0 + rs1;
      #pragma unroll
      for (int k2 = 0; k2 < 2; ++k2) {
        // word0/word2 from regs {0,1}/{4,5}; word1/word3 from {2,3}/{6,7}
        u32 a0 = cvtpk(s[h][8 * k2 + 0], s[h][8 * k2 + 1]);
        u32 b0 = cvtpk(s[h][8 * k2 + 4], s[h][8 * k2 + 5]);
        swap32(a0, b0);
        u32 a1 = cvtpk(s[h][8 * k2 + 2], s[h][8 * k2 + 3]);
        u32 b1 = cvtpk(s[h][8 * k2 + 6], s[h][8 * k2 + 7]);
        swap32(a1, b1);
        u32x4 pw; pw[0] = a0; pw[1] = a1; pw[2] = b0; pw[3] = b1;
        bf16x8 pa = __builtin_bit_cast(bf16x8, pw);
        int ksl = 2 * h + k2;                // kv 16-slice index in [0,4)
        #pragma unroll
        for (int dt = 0; dt < 2; ++dt) {
          bf16x8 bv = ld8(vsb + (((ksl * 2 + hi) * 64) + dt * 32 + l32) * 8);
          accd[dt] = __builtin_amdgcn_mfma_f32_32x32x16_bf16(pa, bv, accd[dt], 0, 0, 0);
        }
      }
    }
    cur = (cur == 2) ? 0 : cur + 1;
  }

  // ---- epilogue: l[q=l32] = own half + partner half ----
  float lsum = l_part + __shfl_xor(l_part, 32);

  if (SPLIT) {
    #pragma unroll
    for (int r = 0; r < 16; ++r) {
      int qrow = (r & 3) + 8 * (r >> 2) + 4 * hi;
      size_t rowb = ((size_t)kz * 65536 + (size_t)bh * S_ + qw + qrow) * D_;
      Opart[rowb + l32]      = accd[0][r];
      Opart[rowb + 32 + l32] = accd[1][r];
    }
    if (hi == 0)
      lpart[(size_t)kz * 65536 + (size_t)bh * S_ + qw + l32] = lsum;
  } else {
    #pragma unroll
    for (int r = 0; r < 16; ++r) {
      int qrow = (r & 3) + 8 * (r >> 2) + 4 * hi;
      float inv = 1.0f / __shfl(lsum, qrow);
      size_t rowb = ((size_t)bh * S_ + qw + qrow) * D_;
      out[rowb + l32]      = accd[0][r] * inv;
      out[rowb + 32 + l32] = accd[1][r] * inv;
    }
  }
}

// ---------------- combine: out = (O0 + O1) / (l0 + l1) --------------------
__global__ __launch_bounds__(256)
void combine_kernel(const float* __restrict__ Opart, const float* __restrict__ lpart,
                    float* __restrict__ out) {
  int t = blockIdx.x * 256 + threadIdx.x;   // 1,048,576 threads
  int row = t >> 4;
  int d4  = (t & 15) * 4;
  float4 o0 = *(const float4*)(Opart + (size_t)row * D_ + d4);
  float4 o1 = *(const float4*)(Opart + (size_t)65536 * D_ + (size_t)row * D_ + d4);
  float inv = 1.0f / (lpart[row] + lpart[65536 + row]);
  float4 o;
  o.x = (o0.x + o1.x) * inv; o.y = (o0.y + o1.y) * inv;
  o.z = (o0.z + o1.z) * inv; o.w = (o0.w + o1.w) * inv;
  *(float4*)(out + (size_t)row * D_ + d4) = o;
}

extern "C" void kernel_launch(void* const* d_in, const int* in_sizes, int n_in,
                              void* d_out, int out_size, void* d_ws, size_t ws_size,
                              hipStream_t stream) {
  const float* Q  = (const float*)d_in[0];
  const float* K  = (const float*)d_in[1];
  const float* V  = (const float*)d_in[2];
  const float* Qp = (const float*)d_in[3];
  const float* Kp = (const float*)d_in[4];
  float* out = (float*)d_out;

  const size_t nKc = (size_t)BH_ * S_ * DQK;   // 8.39M u16
  const size_t nVt = (size_t)BH_ * S_ * D_;    // 4.19M u16
  const size_t nO  = (size_t)2 * 65536 * D_;   // 8.39M f32
  const size_t nL  = (size_t)2 * 65536;        // 131072 f32
  const size_t needSplit = (nO + nL) * 4 + (nKc + nVt) * 2;  // ~59.3 MB

  if (ws_size >= needSplit) {
    float* Opart = (float*)d_ws;
    float* lpart = Opart + nO;
    u16* Kc = (u16*)(lpart + nL);
    u16* Vt = Kc + nKc;
    prep_kernel<<<dim3(4096 + 1024), dim3(256), 0, stream>>>(K, V, Kp, Kc, Vt);
    fa3_kernel<1><<<dim3((S_ / BQ) * BH_ * 2), dim3(512), 0, stream>>>(Q, Qp, Kc, Vt, nullptr, Opart, lpart);
    combine_kernel<<<dim3(4096), dim3(256), 0, stream>>>(Opart, lpart, out);
  } else {
    // ws >= 26 MB path
    u16* Kc = (u16*)d_ws;
    u16* Vt = Kc + nKc;
    prep_kernel<<<dim3(4096 + 1024), dim3(256), 0, stream>>>(K, V, Kp, Kc, Vt);
    fa3_kernel<0><<<dim3((S_ / BQ) * BH_), dim3(512), 0, stream>>>(Q, Qp, Kc, Vt, out, nullptr, nullptr);
  }
}

// Round 9
// 176.604 us; speedup vs baseline: 1.0302x; 1.0302x over previous
//
#include <hip/hip_runtime.h>

#define BH_ 32
#define S_ 2048
#define D_ 64
#define DQK 128
#define BQ 256   // q rows per block (4 waves x 64 q-rows each)

typedef unsigned short u16;
typedef unsigned int u32;
typedef u16 u16x8 __attribute__((ext_vector_type(8)));
typedef u32 u32x4 __attribute__((ext_vector_type(4)));
typedef __bf16 bf16x8 __attribute__((ext_vector_type(8)));
typedef float f32x16 __attribute__((ext_vector_type(16)));

__device__ __forceinline__ u16 f2bf_rne(float f) {
  unsigned u = __builtin_bit_cast(unsigned, f);
  u += 0x7fffu + ((u >> 16) & 1u);
  return (u16)(u >> 16);
}
__device__ __forceinline__ bf16x8 ld8(const u16* p) {
  return __builtin_bit_cast(bf16x8, *(const u16x8*)p);
}
// 16B global -> LDS DMA. LDS dest must be wave-uniform base + lane*16.
__device__ __forceinline__ void g2l16(const u16* g, u16* l) {
  __builtin_amdgcn_global_load_lds(
      (const __attribute__((address_space(1))) unsigned int*)g,
      (__attribute__((address_space(3))) unsigned int*)l, 16, 0, 0);
}
__device__ __forceinline__ u32 cvtpk(float lo, float hi) {
  u32 r;
  asm("v_cvt_pk_bf16_f32 %0, %1, %2" : "=v"(r) : "v"(lo), "v"(hi));
  return r;
}
__device__ __forceinline__ void swap32(u32& a, u32& b) {
  asm("v_permlane32_swap_b32 %0, %1" : "+v"(a), "+v"(b));
}
// NOTE (R3/R4 lesson): never feed MFMA accumulator regs straight into inline
// asm (bare v_exp_f32) -- MFMA-dst->VALU-read hazard nops are only inserted
// for compiler-visible consumers. __builtin_amdgcn_exp2f is the compiler-
// visible bare v_exp_f32: hazard-safe, no OCML range-guard sequence.
__device__ __forceinline__ f32x16 zero16() {
  f32x16 z;
  #pragma unroll
  for (int i = 0; i < 16; ++i) z[i] = 0.f;
  return z;
}

#define COEF 0.1803368801111204f  // (1/8) * log2(e), folded into Q conversion

// ---------------- prep ----------------------------------------------------
// Kc: [bh][kt=32][chunk16B=16][kv=64][8 u16]; Vt: [bh][kt=32][chunk=8][d=64][8].
__global__ __launch_bounds__(256)
void prep_kernel(const float* __restrict__ K, const float* __restrict__ V,
                 const float* __restrict__ Kp,
                 u16* __restrict__ Kc, u16* __restrict__ Vt) {
  __shared__ float Ls[64][65];
  int b = blockIdx.x;
  if (b < 4096) {
    int t = b * 256 + threadIdx.x;          // 1,048,576 threads
    int kv    = t & 63;
    int chunk = (t >> 6) & 15;
    int kt    = (t >> 10) & 31;
    int bh    = t >> 15;
    int s     = kt * 64 + kv;
    int col8  = chunk * 8;
    const float* src = (col8 < 64) ? (K  + ((size_t)bh * S_ + s) * D_ + col8)
                                   : (Kp + ((size_t)bh * S_ + s) * D_ + (col8 - 64));
    float4 v0 = *(const float4*)src;
    float4 v1 = *(const float4*)(src + 4);
    u16x8 w;
    w[0] = f2bf_rne(v0.x); w[1] = f2bf_rne(v0.y); w[2] = f2bf_rne(v0.z); w[3] = f2bf_rne(v0.w);
    w[4] = f2bf_rne(v1.x); w[5] = f2bf_rne(v1.y); w[6] = f2bf_rne(v1.z); w[7] = f2bf_rne(v1.w);
    *(u16x8*)(Kc + ((((size_t)bh * 32 + kt) * 16 + chunk) * 64 + kv) * 8) = w;
  } else {
    // V transpose: one 64(kv) x 64(d) tile per block via LDS
    int id = b - 4096;
    int bh = id >> 5, kt = id & 31;
    int tid = threadIdx.x;
    #pragma unroll
    for (int it = 0; it < 4; ++it) {
      int i = it * 256 + tid;
      int kv = i >> 4, dg = (i & 15) * 4;
      float4 v = *(const float4*)(V + ((size_t)bh * S_ + kt * 64 + kv) * D_ + dg);
      Ls[kv][dg + 0] = v.x; Ls[kv][dg + 1] = v.y;
      Ls[kv][dg + 2] = v.z; Ls[kv][dg + 3] = v.w;
    }
    __syncthreads();
    int d = tid >> 2, kvg = (tid & 3) * 16;
    u16x8 w0, w1;
    #pragma unroll
    for (int j = 0; j < 8; ++j) w0[j] = f2bf_rne(Ls[kvg + j][d]);
    #pragma unroll
    for (int j = 0; j < 8; ++j) w1[j] = f2bf_rne(Ls[kvg + 8 + j][d]);
    u16* base = Vt + ((size_t)bh * 32 + kt) * 4096;
    int c = (tid & 3) * 2;                   // kv-chunk of w0
    *(u16x8*)(base + ((size_t)(c * 64 + d)) * 8)       = w0;
    *(u16x8*)(base + ((size_t)((c + 1) * 64 + d)) * 8) = w1;
  }
}

// ---------------- flash-attention main kernel -----------------------------
// R8: 64 q-rows per wave (two 32-row q-sets) -> each ds_read_b128 of K feeds
// 4 MFMAs, of V feeds 2. LDS-read traffic per 256 q-rows halves (192->96
// reads/tile); QK and PV phases flip from LDS-bound to matrix-bound.
// 4 waves / 256 threads, 2 blocks/CU (grid 512, zero tail), triple-buffered
// K/V DMA + counted vmcnt + raw s_barrier (R7 pipeline, 6 loads/thread/tile).
template <int SPLIT>
__global__ __launch_bounds__(256, 2)
void fa3_kernel(const float* __restrict__ Q, const float* __restrict__ Qp,
                const u16* __restrict__ Kc, const u16* __restrict__ Vtg,
                float* __restrict__ out, float* __restrict__ Opart,
                float* __restrict__ lpart) {
  __shared__ alignas(16) u16 Ks[3][8192];   // [buf][chunk=16][kv=64][8]  3x16KB
  __shared__ alignas(16) u16 Vs[3][4096];   // [buf][chunk=8][d=64][8]    3x8KB

  const int tid  = threadIdx.x;
  const int wave = tid >> 6;                // 0..3
  const int lane = tid & 63;
  const int l32  = lane & 31;
  const int hi   = lane >> 5;

  const int id   = blockIdx.x;
  const int p    = SPLIT ? (id & 63) : (id & 31);   // (bh, z) pair index
  const int qblk = SPLIT ? (id >> 6) : (id >> 5);
  const int bh   = p & 31;
  const int kz   = SPLIT ? (p >> 5) : 0;

  const int qw = qblk * BQ + wave * 64;     // this wave's q base (64 rows)
  const int kt0 = kz * 16;
  const int NKT = SPLIT ? 16 : 32;

  // ---- Q B-frags: bq[g][kstep][j] = Qc[q = qw+g*32+l32][kstep*16+hi*8+j] ----
  bf16x8 bq[2][8];
  #pragma unroll
  for (int g = 0; g < 2; ++g)
    #pragma unroll
    for (int kstep = 0; kstep < 8; ++kstep) {
      int k0 = kstep * 16 + hi * 8;          // wave-uniform Q/Qp select per kstep
      const float* src = (k0 < 64)
          ? (Q  + ((size_t)bh * S_ + qw + g * 32 + l32) * D_ + k0)
          : (Qp + ((size_t)bh * S_ + qw + g * 32 + l32) * D_ + (k0 - 64));
      float4 v0 = *(const float4*)src;
      float4 v1 = *(const float4*)(src + 4);
      u16x8 w;
      w[0] = f2bf_rne(v0.x * COEF); w[1] = f2bf_rne(v0.y * COEF);
      w[2] = f2bf_rne(v0.z * COEF); w[3] = f2bf_rne(v0.w * COEF);
      w[4] = f2bf_rne(v1.x * COEF); w[5] = f2bf_rne(v1.y * COEF);
      w[6] = f2bf_rne(v1.z * COEF); w[7] = f2bf_rne(v1.w * COEF);
      bq[g][kstep] = __builtin_bit_cast(bf16x8, w);
    }

  // ---- staging pointers: 256 threads x 16B = 4KB per round ----
  // K tile (16KB) = 4 rounds, V tile (8KB) = 2 rounds -> 6 g2l16/thread/tile.
  const u16* kcp = Kc  + ((size_t)bh * 32 + kt0) * 8192 + tid * 8;
  const u16* vtp = Vtg + ((size_t)bh * 32 + kt0) * 4096 + tid * 8;

  // prologue: stage tiles 0 and 1
  #pragma unroll
  for (int j = 0; j < 4; ++j) g2l16(kcp + j * 2048, &Ks[0][0] + tid * 8 + j * 2048);
  #pragma unroll
  for (int j = 0; j < 2; ++j) g2l16(vtp + j * 2048, &Vs[0][0] + tid * 8 + j * 2048);
  #pragma unroll
  for (int j = 0; j < 4; ++j) g2l16(kcp + 8192 + j * 2048, &Ks[1][0] + tid * 8 + j * 2048);
  #pragma unroll
  for (int j = 0; j < 2; ++j) g2l16(vtp + 4096 + j * 2048, &Vs[1][0] + tid * 8 + j * 2048);

  f32x16 accd[2][2];
  #pragma unroll
  for (int g = 0; g < 2; ++g) { accd[g][0] = zero16(); accd[g][1] = zero16(); }
  float l_part[2] = {0.f, 0.f};

  int cur = 0;                               // kt % 3
  for (int kt = 0; kt < NKT; ++kt) {
    // ---- own tile-kt loads done (tile kt+1's 6 stay in flight) ----
    if (kt == NKT - 1) asm volatile("s_waitcnt vmcnt(0)" ::: "memory");
    else               asm volatile("s_waitcnt vmcnt(6)" ::: "memory");
    // all waves' tile-kt loads landed; all waves finished compute kt-1
    __builtin_amdgcn_s_barrier();
    // ---- issue DMA for tile kt+2 into buf[(kt+2)%3] == buf[(kt-1)%3] ----
    if (kt + 2 < NKT) {
      int nx = cur + 2; if (nx >= 3) nx -= 3;
      const u16* kg = kcp + (size_t)(kt + 2) * 8192;
      u16* kl = &Ks[nx][0] + tid * 8;
      #pragma unroll
      for (int j = 0; j < 4; ++j) g2l16(kg + j * 2048, kl + j * 2048);
      const u16* vg = vtp + (size_t)(kt + 2) * 4096;
      u16* vl = &Vs[nx][0] + tid * 8;
      #pragma unroll
      for (int j = 0; j < 2; ++j) g2l16(vg + j * 2048, vl + j * 2048);
    }
    __builtin_amdgcn_sched_barrier(0);  // keep DMA issue ahead of compute

    const u16* ksb = &Ks[cur][0];
    const u16* vsb = &Vs[cur][0];

    // ---- S^T = K . Q^T : each K A-frag pair feeds 4 MFMAs (2 q-sets) ----
    f32x16 s[2][2];
    #pragma unroll
    for (int g = 0; g < 2; ++g) { s[g][0] = zero16(); s[g][1] = zero16(); }
    #pragma unroll
    for (int kstep = 0; kstep < 8; ++kstep) {
      bf16x8 akA = ld8(ksb + (((kstep * 2 + hi) * 64) + l32) * 8);
      bf16x8 akB = ld8(ksb + (((kstep * 2 + hi) * 64) + 32 + l32) * 8);
      #pragma unroll
      for (int g = 0; g < 2; ++g) {
        s[g][0] = __builtin_amdgcn_mfma_f32_32x32x16_bf16(akA, bq[g][kstep], s[g][0], 0, 0, 0);
        s[g][1] = __builtin_amdgcn_mfma_f32_32x32x16_bf16(akB, bq[g][kstep], s[g][1], 0, 0, 0);
      }
    }

    // ---- softmax numerator + in-register P redistribution + PV ----
    #pragma unroll
    for (int h = 0; h < 2; ++h) {
      #pragma unroll
      for (int g = 0; g < 2; ++g) {
        float rs0 = 0.f, rs1 = 0.f;
        #pragma unroll
        for (int r = 0; r < 8; ++r) {
          float e0 = __builtin_amdgcn_exp2f(s[g][h][r]);
          float e1 = __builtin_amdgcn_exp2f(s[g][h][8 + r]);
          s[g][h][r] = e0; s[g][h][8 + r] = e1;
          rs0 += e0; rs1 += e1;
        }
        l_part[g] += rs0 + rs1;
      }
      #pragma unroll
      for (int k2 = 0; k2 < 2; ++k2) {
        bf16x8 pa[2];
        #pragma unroll
        for (int g = 0; g < 2; ++g) {
          u32 a0 = cvtpk(s[g][h][8 * k2 + 0], s[g][h][8 * k2 + 1]);
          u32 b0 = cvtpk(s[g][h][8 * k2 + 4], s[g][h][8 * k2 + 5]);
          swap32(a0, b0);
          u32 a1 = cvtpk(s[g][h][8 * k2 + 2], s[g][h][8 * k2 + 3]);
          u32 b1 = cvtpk(s[g][h][8 * k2 + 6], s[g][h][8 * k2 + 7]);
          swap32(a1, b1);
          u32x4 pw; pw[0] = a0; pw[1] = a1; pw[2] = b0; pw[3] = b1;
          pa[g] = __builtin_bit_cast(bf16x8, pw);
        }
        int ksl = 2 * h + k2;                // kv 16-slice index in [0,4)
        #pragma unroll
        for (int dt = 0; dt < 2; ++dt) {
          bf16x8 bv = ld8(vsb + (((ksl * 2 + hi) * 64) + dt * 32 + l32) * 8);
          #pragma unroll
          for (int g = 0; g < 2; ++g)
            accd[g][dt] = __builtin_amdgcn_mfma_f32_32x32x16_bf16(pa[g], bv, accd[g][dt], 0, 0, 0);
        }
      }
    }
    cur = (cur == 2) ? 0 : cur + 1;
  }

  // ---- epilogue ----
  #pragma unroll
  for (int g = 0; g < 2; ++g) {
    float lsum = l_part[g] + __shfl_xor(l_part[g], 32);
    if (SPLIT) {
      #pragma unroll
      for (int r = 0; r < 16; ++r) {
        int qrow = (r & 3) + 8 * (r >> 2) + 4 * hi;
        size_t rowb = ((size_t)kz * 65536 + (size_t)bh * S_ + qw + g * 32 + qrow) * D_;
        Opart[rowb + l32]      = accd[g][0][r];
        Opart[rowb + 32 + l32] = accd[g][1][r];
      }
      if (hi == 0)
        lpart[(size_t)kz * 65536 + (size_t)bh * S_ + qw + g * 32 + l32] = lsum;
    } else {
      #pragma unroll
      for (int r = 0; r < 16; ++r) {
        int qrow = (r & 3) + 8 * (r >> 2) + 4 * hi;
        float inv = 1.0f / __shfl(lsum, qrow);
        size_t rowb = ((size_t)bh * S_ + qw + g * 32 + qrow) * D_;
        out[rowb + l32]      = accd[g][0][r] * inv;
        out[rowb + 32 + l32] = accd[g][1][r] * inv;
      }
    }
  }
}

// ---------------- combine: out = (O0 + O1) / (l0 + l1) --------------------
__global__ __launch_bounds__(256)
void combine_kernel(const float* __restrict__ Opart, const float* __restrict__ lpart,
                    float* __restrict__ out) {
  int t = blockIdx.x * 256 + threadIdx.x;   // 1,048,576 threads
  int row = t >> 4;
  int d4  = (t & 15) * 4;
  float4 o0 = *(const float4*)(Opart + (size_t)row * D_ + d4);
  float4 o1 = *(const float4*)(Opart + (size_t)65536 * D_ + (size_t)row * D_ + d4);
  float inv = 1.0f / (lpart[row] + lpart[65536 + row]);
  float4 o;
  o.x = (o0.x + o1.x) * inv; o.y = (o0.y + o1.y) * inv;
  o.z = (o0.z + o1.z) * inv; o.w = (o0.w + o1.w) * inv;
  *(float4*)(out + (size_t)row * D_ + d4) = o;
}

extern "C" void kernel_launch(void* const* d_in, const int* in_sizes, int n_in,
                              void* d_out, int out_size, void* d_ws, size_t ws_size,
                              hipStream_t stream) {
  const float* Q  = (const float*)d_in[0];
  const float* K  = (const float*)d_in[1];
  const float* V  = (const float*)d_in[2];
  const float* Qp = (const float*)d_in[3];
  const float* Kp = (const float*)d_in[4];
  float* out = (float*)d_out;

  const size_t nKc = (size_t)BH_ * S_ * DQK;   // 8.39M u16
  const size_t nVt = (size_t)BH_ * S_ * D_;    // 4.19M u16
  const size_t nO  = (size_t)2 * 65536 * D_;   // 8.39M f32
  const size_t nL  = (size_t)2 * 65536;        // 131072 f32
  const size_t needSplit = (nO + nL) * 4 + (nKc + nVt) * 2;  // ~59.3 MB

  if (ws_size >= needSplit) {
    float* Opart = (float*)d_ws;
    float* lpart = Opart + nO;
    u16* Kc = (u16*)(lpart + nL);
    u16* Vt = Kc + nKc;
    prep_kernel<<<dim3(4096 + 1024), dim3(256), 0, stream>>>(K, V, Kp, Kc, Vt);
    fa3_kernel<1><<<dim3((S_ / BQ) * BH_ * 2), dim3(256), 0, stream>>>(Q, Qp, Kc, Vt, nullptr, Opart, lpart);
    combine_kernel<<<dim3(4096), dim3(256), 0, stream>>>(Opart, lpart, out);
  } else {
    // ws >= 26 MB path
    u16* Kc = (u16*)d_ws;
    u16* Vt = Kc + nKc;
    prep_kernel<<<dim3(4096 + 1024), dim3(256), 0, stream>>>(K, V, Kp, Kc, Vt);
    fa3_kernel<0><<<dim3((S_ / BQ) * BH_), dim3(256), 0, stream>>>(Q, Qp, Kc, Vt, out, nullptr, nullptr);
  }
}